// Round 1
// baseline (607.570 us; speedup 1.0000x reference)
//
#include <hip/hip_runtime.h>
#include <hip/hip_bf16.h>
#include <math.h>

typedef __bf16 bf16;
typedef __bf16 bf16x8 __attribute__((ext_vector_type(8)));
typedef __bf16 bf16x4 __attribute__((ext_vector_type(4)));
typedef float f32x4 __attribute__((ext_vector_type(4)));

#define S_ 4096
#define D_ 1024
#define H_ 16
#define HD_ 64
#define N3_ 3072

// ---------------- fp32 -> bf16 convert (vectorized) ----------------
__global__ __launch_bounds__(256) void cvt_f32_bf16(const float* __restrict__ in,
                                                    bf16* __restrict__ out) {
  int i = (blockIdx.x * 256 + threadIdx.x) * 4;
  float4 v = *(const float4*)(in + i);
  bf16x4 o;
  o.x = (bf16)v.x; o.y = (bf16)v.y; o.z = (bf16)v.z; o.w = (bf16)v.w;
  *(bf16x4*)(out + i) = o;
}

// ---------------- tiled transpose fp32 -> bf16 : out[C][R] = in[R][C] ----------------
__global__ __launch_bounds__(256) void transpose_f32_bf16(const float* __restrict__ in,
                                                          bf16* __restrict__ out,
                                                          int R, int C, int ldin, int col0) {
  __shared__ float t[32][33];
  int bx = blockIdx.x * 32;  // column base (input)
  int by = blockIdx.y * 32;  // row base (input)
  int tx = threadIdx.x & 31, ty = threadIdx.x >> 5;  // 32 x 8
#pragma unroll
  for (int i = 0; i < 4; ++i)
    t[ty + i * 8][tx] = in[(size_t)(by + ty + i * 8) * ldin + col0 + bx + tx];
  __syncthreads();
#pragma unroll
  for (int i = 0; i < 4; ++i)
    out[(size_t)(bx + ty + i * 8) * R + by + tx] = (bf16)t[tx][ty + i * 8];
}

// ---------------- tiled transpose bf16 -> bf16 : out[C][R] = in[R][col0+C] ----------------
__global__ __launch_bounds__(256) void transpose_bf16(const bf16* __restrict__ in,
                                                      bf16* __restrict__ out,
                                                      int R, int C, int ldin, int col0) {
  __shared__ bf16 t[32][33];
  int bx = blockIdx.x * 32;
  int by = blockIdx.y * 32;
  int tx = threadIdx.x & 31, ty = threadIdx.x >> 5;
#pragma unroll
  for (int i = 0; i < 4; ++i)
    t[ty + i * 8][tx] = in[(size_t)(by + ty + i * 8) * ldin + col0 + bx + tx];
  __syncthreads();
#pragma unroll
  for (int i = 0; i < 4; ++i)
    out[(size_t)(bx + ty + i * 8) * R + by + tx] = t[tx][ty + i * 8];
}

// ---------------- bf16 GEMM: C[M][N] = A[M][K] * Bt[N][K]^T + bias ----------------
// 128x128 block tile, BK=32, 4 waves in 2x2, each wave 64x64 via 4x4 MFMA 16x16x32.
constexpr int AST = 56;  // LDS row stride in elems: 112 B (16B-aligned, 2-way bank alias only)

__global__ __launch_bounds__(256) void gemm_bt(const bf16* __restrict__ A,
                                               const bf16* __restrict__ Bt,
                                               const float* __restrict__ bias,
                                               bf16* __restrict__ outb,
                                               float* __restrict__ outf,
                                               int M, int N, int K) {
  __shared__ bf16 sA[128 * AST];
  __shared__ bf16 sB[128 * AST];
  const int tid = threadIdx.x;
  const int wave = tid >> 6, lane = tid & 63;
  const int col = lane & 15, quad = lane >> 4;
  const int wm = (wave & 1) * 64, wn = (wave >> 1) * 64;
  const long bm = (long)blockIdx.x * 128, bn = (long)blockIdx.y * 128;

  f32x4 acc[4][4] = {};

  for (int kb = 0; kb < K; kb += 32) {
    __syncthreads();
#pragma unroll
    for (int i = 0; i < 2; ++i) {
      int c = i * 256 + tid;
      int row = c >> 2, c8 = c & 3;
      *(int4*)(&sA[row * AST + c8 * 8]) =
          *(const int4*)(&A[(bm + row) * (long)K + kb + c8 * 8]);
      *(int4*)(&sB[row * AST + c8 * 8]) =
          *(const int4*)(&Bt[(bn + row) * (long)K + kb + c8 * 8]);
    }
    __syncthreads();

    bf16x8 af[4], bfr[4];
#pragma unroll
    for (int t = 0; t < 4; ++t) {
      af[t]  = *(const bf16x8*)(&sA[(wm + t * 16 + col) * AST + quad * 8]);
      bfr[t] = *(const bf16x8*)(&sB[(wn + t * 16 + col) * AST + quad * 8]);
    }
#pragma unroll
    for (int mt = 0; mt < 4; ++mt)
#pragma unroll
      for (int nt = 0; nt < 4; ++nt)
        acc[mt][nt] = __builtin_amdgcn_mfma_f32_16x16x32_bf16(af[mt], bfr[nt], acc[mt][nt], 0, 0, 0);
  }

#pragma unroll
  for (int mt = 0; mt < 4; ++mt) {
#pragma unroll
    for (int nt = 0; nt < 4; ++nt) {
      long gn = bn + wn + nt * 16 + col;
      float bv = bias ? bias[gn] : 0.f;
#pragma unroll
      for (int i = 0; i < 4; ++i) {
        long gm = bm + wm + mt * 16 + quad * 4 + i;
        float v = acc[mt][nt][i] + bv;
        if (outf) outf[gm * N + gn] = v;
        else      outb[gm * N + gn] = (bf16)v;
      }
    }
  }
}

// ---------------- causal flash attention ----------------
// qkv: bf16 [S][3072]  (cols 0..1023=Q, 1024..2047=K, 2048..3071=V)
// vT : bf16 [H][HD][S]
// out: bf16 [S][D]
// grid (S/64, H), block 256: each wave handles 16 q-rows.
constexpr int PST = 56;  // P-tile LDS row stride (elems)

__global__ __launch_bounds__(256) void attn_kernel(const bf16* __restrict__ qkv,
                                                   const bf16* __restrict__ vT,
                                                   bf16* __restrict__ out) {
  __shared__ bf16 plds[4][16 * PST];
  const int h = blockIdx.y;
  const int qb = (int)(gridDim.x - 1 - blockIdx.x);  // long rows dispatch first
  const int wave = threadIdx.x >> 6, lane = threadIdx.x & 63;
  const int col = lane & 15, quad = lane >> 4;
  const int qbase = qb * 64 + wave * 16;
  bf16* pw = &plds[wave][0];

  // Q fragments (A-operand layout): lane holds Q[qbase+col][koff + quad*8 .. +7]
  const bf16* qp = qkv + (size_t)(qbase + col) * N3_ + h * HD_;
  bf16x8 aq0 = *(const bf16x8*)(qp + quad * 8);
  bf16x8 aq1 = *(const bf16x8*)(qp + 32 + quad * 8);

  float m_r[4], l_r[4];
  f32x4 acc[4] = {};
#pragma unroll
  for (int r = 0; r < 4; ++r) { m_r[r] = -1e30f; l_r[r] = 0.f; }

  const bf16* vtb = vT + (size_t)h * HD_ * S_;
  const float L2E = 1.44269504088896f;
  const int kend = qbase + 16;

  for (int kb = 0; kb < kend; kb += 32) {
    // --- QK^T: two 16x16 score tiles (keys kb..kb+15, kb+16..kb+31) ---
    f32x4 s[2];
#pragma unroll
    for (int t = 0; t < 2; ++t) {
      const bf16* kp = qkv + (size_t)(kb + t * 16 + col) * N3_ + D_ + h * HD_;
      bf16x8 bk0 = *(const bf16x8*)(kp + quad * 8);
      bf16x8 bk1 = *(const bf16x8*)(kp + 32 + quad * 8);
      f32x4 z = {};
      z = __builtin_amdgcn_mfma_f32_16x16x32_bf16(aq0, bk0, z, 0, 0, 0);
      s[t] = __builtin_amdgcn_mfma_f32_16x16x32_bf16(aq1, bk1, z, 0, 0, 0);
    }

    float sc[2][4];
    if (kb + 31 > qbase) {  // diagonal chunk: apply causal mask
#pragma unroll
      for (int t = 0; t < 2; ++t)
#pragma unroll
        for (int r = 0; r < 4; ++r) {
          int key = kb + t * 16 + col;
          int row = qbase + quad * 4 + r;
          sc[t][r] = (key > row) ? -1e30f : s[t][r] * 0.125f;
        }
    } else {
#pragma unroll
      for (int t = 0; t < 2; ++t)
#pragma unroll
        for (int r = 0; r < 4; ++r) sc[t][r] = s[t][r] * 0.125f;
    }

    // --- online softmax (row = quad*4 + r; 16 key-cols spread across quad lanes) ---
    float mx[4];
#pragma unroll
    for (int r = 0; r < 4; ++r) mx[r] = fmaxf(sc[0][r], sc[1][r]);
#pragma unroll
    for (int m = 1; m <= 8; m <<= 1)
#pragma unroll
      for (int r = 0; r < 4; ++r) mx[r] = fmaxf(mx[r], __shfl_xor(mx[r], m));

    float alpha[4], p[2][4], rs[4];
#pragma unroll
    for (int r = 0; r < 4; ++r) {
      float mnew = fmaxf(m_r[r], mx[r]);
      alpha[r] = __builtin_exp2f((m_r[r] - mnew) * L2E);
      m_r[r] = mnew;
      p[0][r] = __builtin_exp2f((sc[0][r] - mnew) * L2E);
      p[1][r] = __builtin_exp2f((sc[1][r] - mnew) * L2E);
      rs[r] = p[0][r] + p[1][r];
    }
#pragma unroll
    for (int m = 1; m <= 8; m <<= 1)
#pragma unroll
      for (int r = 0; r < 4; ++r) rs[r] += __shfl_xor(rs[r], m);
#pragma unroll
    for (int r = 0; r < 4; ++r) l_r[r] = l_r[r] * alpha[r] + rs[r];

    // rescale O accumulator
#pragma unroll
    for (int n = 0; n < 4; ++n)
#pragma unroll
      for (int r = 0; r < 4; ++r) acc[n][r] *= alpha[r];

    // --- P: C-layout -> A-layout via per-wave LDS tile ---
#pragma unroll
    for (int t = 0; t < 2; ++t)
#pragma unroll
      for (int r = 0; r < 4; ++r)
        pw[(quad * 4 + r) * PST + t * 16 + col] = (bf16)p[t][r];
    __asm__ volatile("s_waitcnt lgkmcnt(0)" ::: "memory");
    bf16x8 ap = *(const bf16x8*)(&pw[col * PST + quad * 8]);

    // --- PV: acc[n] += P[16x32] * V[kb..kb+31][n*16..n*16+15] ---
#pragma unroll
    for (int n = 0; n < 4; ++n) {
      bf16x8 bv = *(const bf16x8*)(&vtb[(size_t)(n * 16 + col) * S_ + kb + quad * 8]);
      acc[n] = __builtin_amdgcn_mfma_f32_16x16x32_bf16(ap, bv, acc[n], 0, 0, 0);
    }
  }

  // epilogue: O / l, write bf16 [S][D]
  float invl[4];
#pragma unroll
  for (int r = 0; r < 4; ++r) invl[r] = 1.0f / l_r[r];
#pragma unroll
  for (int n = 0; n < 4; ++n)
#pragma unroll
    for (int r = 0; r < 4; ++r)
      out[(size_t)(qbase + quad * 4 + r) * D_ + h * HD_ + n * 16 + col] =
          (bf16)(acc[n][r] * invl[r]);
}

// ---------------- host orchestration ----------------
extern "C" void kernel_launch(void* const* d_in, const int* in_sizes, int n_in,
                              void* d_out, int out_size, void* d_ws, size_t ws_size,
                              hipStream_t stream) {
  const float* x      = (const float*)d_in[0];
  const float* w_qkv  = (const float*)d_in[1];
  const float* b_qkv  = (const float*)d_in[2];
  const float* w_proj = (const float*)d_in[3];
  const float* b_proj = (const float*)d_in[4];
  float* out = (float*)d_out;

  bf16* xb     = (bf16*)d_ws;                       // [4096][1024]   8 MB
  bf16* wqkvT  = xb + (size_t)S_ * D_;              // [3072][1024]   6 MB
  bf16* wprojT = wqkvT + (size_t)N3_ * D_;          // [1024][1024]   2 MB
  bf16* qkv    = wprojT + (size_t)D_ * D_;          // [4096][3072]  24 MB
  bf16* vT     = qkv + (size_t)S_ * N3_;            // [16][64][4096] 8 MB
  bf16* attn   = vT + (size_t)D_ * S_;              // [4096][1024]   8 MB

  // 1. convert x to bf16
  cvt_f32_bf16<<<dim3((S_ * D_) / 1024), 256, 0, stream>>>(x, xb);
  // 2. transpose weights to [N][K] bf16
  transpose_f32_bf16<<<dim3(N3_ / 32, D_ / 32), 256, 0, stream>>>(w_qkv, wqkvT, D_, N3_, N3_, 0);
  transpose_f32_bf16<<<dim3(D_ / 32, D_ / 32), 256, 0, stream>>>(w_proj, wprojT, D_, D_, D_, 0);
  // 3. QKV GEMM: [4096][3072] = xb * wqkvT^T + b_qkv
  gemm_bt<<<dim3(S_ / 128, N3_ / 128), 256, 0, stream>>>(xb, wqkvT, b_qkv, qkv, nullptr,
                                                         S_, N3_, D_);
  // 4. V transpose: vT[h*64+hd][s] = qkv[s][2048 + h*64 + hd]
  transpose_bf16<<<dim3(D_ / 32, S_ / 32), 256, 0, stream>>>(qkv, vT, S_, D_, N3_, 2 * D_);
  // 5. flash attention
  attn_kernel<<<dim3(S_ / 64, H_), 256, 0, stream>>>(qkv, vT, attn);
  // 6. output projection -> fp32
  gemm_bt<<<dim3(S_ / 128, D_ / 128), 256, 0, stream>>>(attn, wprojT, b_proj, nullptr, out,
                                                        S_, D_, D_);
}